// Round 14
// baseline (353.058 us; speedup 1.0000x reference)
//
#include <hip/hip_runtime.h>

#define N_NODES 65536
#define B_G     16
#define NPG_    4096
#define H_H     2
#define D_D     64
#define HD      128
#define E_E     524288
#define D_OUT   64

// ---------------- degree / CSR build ----------------

__global__ void deg_kernel(const int* __restrict__ col, int* __restrict__ degi) {
    int e = blockIdx.x * 256 + threadIdx.x;
    if (e < E_E) atomicAdd(&degi[col[e]], 1);
}

__global__ void scan1(const int* __restrict__ degi, int* __restrict__ ptr,
                      int* __restrict__ bsums, float* __restrict__ dinv) {
    __shared__ int lds[256];
    int t = threadIdx.x;
    int i = blockIdx.x * 256 + t;
    int v = degi[i];
    dinv[i] = (v > 0) ? (1.0f / sqrtf((float)v)) : 0.0f;
    lds[t] = v;
    __syncthreads();
    for (int off = 1; off < 256; off <<= 1) {
        int tmp = (t >= off) ? lds[t - off] : 0;
        __syncthreads();
        lds[t] += tmp;
        __syncthreads();
    }
    ptr[i] = lds[t] - v;
    if (t == 255) bsums[blockIdx.x] = lds[255];
}

__global__ void scan3(int* __restrict__ ptr, const int* __restrict__ bsums) {
    __shared__ int red[256];
    int t = threadIdx.x;
    red[t] = (t < (int)blockIdx.x) ? bsums[t] : 0;
    __syncthreads();
    for (int off = 128; off > 0; off >>= 1) {
        if (t < off) red[t] += red[t + off];
        __syncthreads();
    }
    int i = blockIdx.x * 256 + t;
    ptr[i] += red[0];
    if (i == 0) ptr[N_NODES] = E_E;
}

__global__ void scatter_kernel(const int* __restrict__ row, const int* __restrict__ col,
                               const int* __restrict__ ptr, int* __restrict__ cursor,
                               const float* __restrict__ dinv,
                               int2* __restrict__ ep) {
    int e = blockIdx.x * 256 + threadIdx.x;
    if (e < E_E) {
        int c = col[e], r = row[e];
        int p = ptr[c] + atomicAdd(&cursor[c], 1);
        ep[p] = make_int2(r, __float_as_int(dinv[c] * dinv[r]));
    }
}

// ---------------- fused k-proj + normalize + K^T X per (bh, 64-node chunk) ----------------
// grid 2048 = bh(32) x chunk(64). LDS: x 16KB + W 16KB + kt 16KB = 48KB -> 3 blocks/CU.
// x-tile staged once serves the projection AND the X side of the product; k never
// leaves LDS. Partials (64 chunks per bh) reduced by kvs_reduce.
__global__ __launch_bounds__(256) void kvskp_kernel(
    const float* __restrict__ x,
    const float* __restrict__ Wk, const float* __restrict__ bk,
    float* __restrict__ partials, float* __restrict__ ksum, float* __restrict__ xsum) {
    __shared__ float4 xt4[64 * 16];    // [node][k4] linear
    __shared__ float4 wt4[16 * 64];    // [k4][c] = Wk[4k4+r][h*64+c]
    __shared__ float4 kt4[64 * 16];    // normalized k [node][d4]
    int bid = blockIdx.x;
    int chunk = bid & 63;
    int bh = bid >> 6;
    int b = bh >> 1, h = bh & 1;
    int node0 = b * NPG_ + chunk * 64;
    int t = threadIdx.x;

    const float4* xg = (const float4*)(x + (size_t)node0 * 64);
    for (int i = t; i < 1024; i += 256) xt4[i] = xg[i];
    for (int i = t; i < 1024; i += 256) {
        int k4 = i >> 6, c = i & 63;
        int cc = h * 64 + c;
        wt4[i] = make_float4(Wk[(4 * k4 + 0) * 128 + cc], Wk[(4 * k4 + 1) * 128 + cc],
                             Wk[(4 * k4 + 2) * 128 + cc], Wk[(4 * k4 + 3) * 128 + cc]);
    }
    __syncthreads();

    int cg = t & 15;
    int ns = t >> 4;
    int s = ns & 3;
    int n_t = ns * 4;
    float* ktf = (float*)kt4;

    {   // k projection (y0-proven structure, XOR iteration order)
        float acc[4][4] = {{0.f}};
        for (int k4 = 0; k4 < 16; ++k4) {
            int kk = k4 ^ s;
            float4 wv[4];
#pragma unroll
            for (int j = 0; j < 4; ++j) wv[j] = wt4[kk * 64 + cg + 16 * j];
#pragma unroll
            for (int i = 0; i < 4; ++i) {
                float4 xv = xt4[(n_t + i) * 16 + kk];
#pragma unroll
                for (int j = 0; j < 4; ++j)
                    acc[i][j] += wv[j].x * xv.x + wv[j].y * xv.y +
                                 wv[j].z * xv.z + wv[j].w * xv.w;
            }
        }
        float bcol[4];
#pragma unroll
        for (int j = 0; j < 4; ++j) bcol[j] = bk[h * 64 + cg + 16 * j];
#pragma unroll
        for (int i = 0; i < 4; ++i) {
#pragma unroll
            for (int j = 0; j < 4; ++j) acc[i][j] += bcol[j];
            float sq = acc[i][0] * acc[i][0] + acc[i][1] * acc[i][1] +
                       acc[i][2] * acc[i][2] + acc[i][3] * acc[i][3];
#pragma unroll
            for (int off = 8; off > 0; off >>= 1) sq += __shfl_xor(sq, off);
            float r = rsqrtf(sq);
#pragma unroll
            for (int j = 0; j < 4; ++j)
                ktf[(n_t + i) * 64 + cg + 16 * j] = acc[i][j] * r;
        }
    }
    __syncthreads();

    // K^T X over the 64-node chunk: thread = 4m x 4d
    int m0 = ns * 4, d0 = cg * 4;
    float acc[4][4] = {{0.f}};
    float ksacc[4] = {0.f, 0.f, 0.f, 0.f};
    float xsacc[4] = {0.f, 0.f, 0.f, 0.f};
    for (int l = 0; l < 64; ++l) {
        float4 kv = *(const float4*)(ktf + l * 64 + m0);   // broadcast over cg
        float4 xv = xt4[l * 16 + cg];
        float kk[4] = {kv.x, kv.y, kv.z, kv.w};
        float xx[4] = {xv.x, xv.y, xv.z, xv.w};
#pragma unroll
        for (int i = 0; i < 4; ++i)
#pragma unroll
            for (int j = 0; j < 4; ++j) acc[i][j] += kk[i] * xx[j];
        if (cg == 0) {
#pragma unroll
            for (int i = 0; i < 4; ++i) ksacc[i] += kk[i];
        }
        if (ns == 0) {
#pragma unroll
            for (int j = 0; j < 4; ++j) xsacc[j] += xx[j];
        }
    }
    float* pout = partials + (size_t)bid * 4096;
#pragma unroll
    for (int i = 0; i < 4; ++i)
        *(float4*)(pout + (m0 + i) * 64 + d0) =
            make_float4(acc[i][0], acc[i][1], acc[i][2], acc[i][3]);
    if (cg == 0) {
#pragma unroll
        for (int i = 0; i < 4; ++i) atomicAdd(&ksum[bh * 64 + m0 + i], ksacc[i]);
    }
    if (ns == 0 && h == 0) {
#pragma unroll
        for (int j = 0; j < 4; ++j) atomicAdd(&xsum[b * 64 + d0 + j], xsacc[j]);
    }
}

__global__ __launch_bounds__(256) void kvs_reduce(
    const float* __restrict__ partials, float* __restrict__ kvs) {
    int i = blockIdx.x * 256 + threadIdx.x;
    int bh = i >> 12, elem = i & 4095;
    const float* p = partials + (size_t)bh * 64 * 4096 + elem;
    float s = 0.f;
#pragma unroll
    for (int c = 0; c < 64; ++c) s += p[c * 4096];
    kvs[i] = s;
}

// ---------------- M_bh = KVS_bh @ Wo_h ; C_bh = xsum_b @ Wo_h ----------------
__global__ __launch_bounds__(256) void mwo_kernel(
    const float* __restrict__ kvs, const float* __restrict__ Wo,
    const float* __restrict__ xsum, float* __restrict__ M, float* __restrict__ C) {
    __shared__ float kv_l[64 * 64];
    __shared__ float wo_l[64 * 64];
    __shared__ float xs_l[64];
    int bh = blockIdx.x;
    int b = bh >> 1, h = bh & 1;
    int t = threadIdx.x;
    const float4* kvg = (const float4*)(kvs + (size_t)bh * 4096);
    for (int i = t; i < 1024; i += 256) ((float4*)kv_l)[i] = kvg[i];
    for (int i = t; i < 1024; i += 256) {
        int d = i >> 4;
        ((float4*)wo_l)[i] = *(const float4*)(Wo + (size_t)(h * 64 + d) * 64 + (i & 15) * 4);
    }
    if (t < 64) xs_l[t] = xsum[b * 64 + t];
    __syncthreads();

    int ccol = t & 15, mrow = t >> 4;
    int m0 = mrow * 4, c0 = ccol * 4;
    float acc[4][4] = {{0.f}};
    float cacc[4] = {0.f, 0.f, 0.f, 0.f};
    for (int d = 0; d < 64; ++d) {
        float4 wv = *(const float4*)(wo_l + d * 64 + c0);
        float kvv[4];
#pragma unroll
        for (int i = 0; i < 4; ++i) kvv[i] = kv_l[(m0 + i) * 64 + d];
#pragma unroll
        for (int i = 0; i < 4; ++i) {
            acc[i][0] += kvv[i] * wv.x; acc[i][1] += kvv[i] * wv.y;
            acc[i][2] += kvv[i] * wv.z; acc[i][3] += kvv[i] * wv.w;
        }
        if (mrow == 0) {
            float xv = xs_l[d];
            cacc[0] += xv * wv.x; cacc[1] += xv * wv.y;
            cacc[2] += xv * wv.z; cacc[3] += xv * wv.w;
        }
    }
    float* mo = M + (size_t)bh * 4096;
#pragma unroll
    for (int i = 0; i < 4; ++i)
        *(float4*)(mo + (m0 + i) * 64 + c0) =
            make_float4(acc[i][0], acc[i][1], acc[i][2], acc[i][3]);
    if (mrow == 0)
        *(float4*)(C + bh * 64 + c0) = make_float4(cacc[0], cacc[1], cacc[2], cacc[3]);
}

// ---------------- fused q-proj + attn@Wo ----------------
// Block = 64 nodes; per h: stage Wq-half -> project+normalize q into LDS qt ->
// restage SAME LDS slot with M -> GEMM (qt @ M) + den. qs never hits global.
// LDS: x 16 + union(Wq,M) 16 + qt 16 = 48KB -> 3 blocks/CU.
__global__ __launch_bounds__(256) void fatt_kernel(
    const float* __restrict__ x,
    const float* __restrict__ Wq, const float* __restrict__ bq,
    const float* __restrict__ M, const float* __restrict__ C,
    const float* __restrict__ ksum, float* __restrict__ a) {
    __shared__ float4 xt4[64 * 16];    // x [node][k4] linear
    __shared__ float4 wu4[16 * 64];    // union: Wq-half, then M
    __shared__ float4 qt4[64 * 16];    // normalized q [node][d4]
    __shared__ float4 ksv[16];
    __shared__ float csv[64];
    int nb = blockIdx.x * 64;
    int b = nb >> 12;
    int t = threadIdx.x;
    int cg = t & 15;
    int ns = t >> 4;
    int sw = ns & 3;
    int n_t = ns * 4;
    float* qtf = (float*)qt4;

    const float4* xg = (const float4*)(x + (size_t)nb * 64);
    for (int i = t; i < 1024; i += 256) xt4[i] = xg[i];

    float acc[4][4] = {{0.f}};

    for (int h = 0; h < 2; ++h) {
        int bh = b * 2 + h;
        // stage Wq head-half
        __syncthreads();
        for (int i = t; i < 1024; i += 256) {
            int k4 = i >> 6, c = i & 63;
            int cc = h * 64 + c;
            wu4[i] = make_float4(Wq[(4 * k4 + 0) * 128 + cc], Wq[(4 * k4 + 1) * 128 + cc],
                                 Wq[(4 * k4 + 2) * 128 + cc], Wq[(4 * k4 + 3) * 128 + cc]);
        }
        __syncthreads();
        {   // q projection + normalize -> qt
            float qa[4][4] = {{0.f}};
            for (int k4 = 0; k4 < 16; ++k4) {
                int kk = k4 ^ sw;
                float4 wv[4];
#pragma unroll
                for (int j = 0; j < 4; ++j) wv[j] = wu4[kk * 64 + cg + 16 * j];
#pragma unroll
                for (int i = 0; i < 4; ++i) {
                    float4 xv = xt4[(n_t + i) * 16 + kk];
#pragma unroll
                    for (int j = 0; j < 4; ++j)
                        qa[i][j] += wv[j].x * xv.x + wv[j].y * xv.y +
                                    wv[j].z * xv.z + wv[j].w * xv.w;
                }
            }
            float bcol[4];
#pragma unroll
            for (int j = 0; j < 4; ++j) bcol[j] = bq[h * 64 + cg + 16 * j];
#pragma unroll
            for (int i = 0; i < 4; ++i) {
#pragma unroll
                for (int j = 0; j < 4; ++j) qa[i][j] += bcol[j];
                float sq = qa[i][0] * qa[i][0] + qa[i][1] * qa[i][1] +
                           qa[i][2] * qa[i][2] + qa[i][3] * qa[i][3];
#pragma unroll
                for (int off = 8; off > 0; off >>= 1) sq += __shfl_xor(sq, off);
                float r = rsqrtf(sq);
#pragma unroll
                for (int j = 0; j < 4; ++j)
                    qtf[(n_t + i) * 64 + cg + 16 * j] = qa[i][j] * r;
            }
        }
        __syncthreads();
        // restage wu4 with M; load ksum/C
        const float* mp = M + (size_t)bh * 4096;
        for (int i = t; i < 1024; i += 256) {
            int k4 = i >> 6, c = i & 63;
            wu4[i] = make_float4(mp[(4 * k4 + 0) * 64 + c], mp[(4 * k4 + 1) * 64 + c],
                                 mp[(4 * k4 + 2) * 64 + c], mp[(4 * k4 + 3) * 64 + c]);
        }
        if (t < 16) ksv[t] = *(const float4*)(ksum + bh * 64 + 4 * t);
        if (t < 64) csv[t] = C[bh * 64 + t];
        __syncthreads();

        float pacc[4][4] = {{0.f}};
        float den[4] = {0.f, 0.f, 0.f, 0.f};
        for (int k4 = 0; k4 < 16; ++k4) {
            int kk = k4 ^ sw;
            float4 kv = ksv[kk];
            float4 wv[4];
#pragma unroll
            for (int j = 0; j < 4; ++j) wv[j] = wu4[kk * 64 + cg + 16 * j];
#pragma unroll
            for (int i = 0; i < 4; ++i) {
                float4 xv = qt4[(n_t + i) * 16 + kk];
                den[i] += kv.x * xv.x + kv.y * xv.y + kv.z * xv.z + kv.w * xv.w;
#pragma unroll
                for (int j = 0; j < 4; ++j)
                    pacc[i][j] += wv[j].x * xv.x + wv[j].y * xv.y +
                                  wv[j].z * xv.z + wv[j].w * xv.w;
            }
        }
        float cc[4];
#pragma unroll
        for (int j = 0; j < 4; ++j) cc[j] = csv[cg + 16 * j];
#pragma unroll
        for (int i = 0; i < 4; ++i) {
            float inv = 1.0f / (den[i] + 16.0f);
#pragma unroll
            for (int j = 0; j < 4; ++j) acc[i][j] += (pacc[i][j] + cc[j]) * inv;
        }
    }

#pragma unroll
    for (int i = 0; i < 4; ++i)
#pragma unroll
        for (int j = 0; j < 4; ++j)
            a[(size_t)(nb + n_t + i) * 64 + cg + 16 * j] = acc[i][j];
}

// ---------------- y0 = x @ (Wo_top + Wo_bot) (proven) ----------------
__global__ __launch_bounds__(256) void y0_kernel(
    const float* __restrict__ x, const float* __restrict__ Wo,
    float* __restrict__ y0) {
    __shared__ float4 wt4[16 * 64];
    __shared__ float4 xt4[64 * 16];
    int t = threadIdx.x;
    int nb = blockIdx.x * 64;

    for (int i = t; i < 1024; i += 256) {
        int k4 = i >> 6, c = i & 63;
        wt4[i] = make_float4(
            Wo[(4 * k4 + 0) * 64 + c] + Wo[(4 * k4 + 64) * 64 + c],
            Wo[(4 * k4 + 1) * 64 + c] + Wo[(4 * k4 + 65) * 64 + c],
            Wo[(4 * k4 + 2) * 64 + c] + Wo[(4 * k4 + 66) * 64 + c],
            Wo[(4 * k4 + 3) * 64 + c] + Wo[(4 * k4 + 67) * 64 + c]);
    }
    const float4* xg = (const float4*)(x + (size_t)nb * 64);
    for (int i = t; i < 1024; i += 256) xt4[i] = xg[i];
    __syncthreads();

    int cg = t & 15;
    int ns = t >> 4;
    int s = ns & 3;
    int n_t = ns * 4;

    float acc[4][4] = {{0.f}};
#pragma unroll 4
    for (int k4 = 0; k4 < 16; ++k4) {
        int kk = k4 ^ s;
        float4 xv0 = xt4[(n_t + 0) * 16 + kk];
        float4 xv1 = xt4[(n_t + 1) * 16 + kk];
        float4 xv2 = xt4[(n_t + 2) * 16 + kk];
        float4 xv3 = xt4[(n_t + 3) * 16 + kk];
#pragma unroll
        for (int j = 0; j < 4; ++j) {
            float4 wv = wt4[kk * 64 + cg + 16 * j];
            acc[0][j] += wv.x * xv0.x + wv.y * xv0.y + wv.z * xv0.z + wv.w * xv0.w;
            acc[1][j] += wv.x * xv1.x + wv.y * xv1.y + wv.z * xv1.z + wv.w * xv1.w;
            acc[2][j] += wv.x * xv2.x + wv.y * xv2.y + wv.z * xv2.z + wv.w * xv2.w;
            acc[3][j] += wv.x * xv3.x + wv.y * xv3.y + wv.z * xv3.z + wv.w * xv3.w;
        }
    }
#pragma unroll
    for (int i = 0; i < 4; ++i)
#pragma unroll
        for (int j = 0; j < 4; ++j)
            y0[(size_t)(nb + n_t + i) * 64 + cg + 16 * j] = acc[i][j];
}

// ---------------- GCN step in 64-col space: single 16-slot batch ----------------
template <int LAST>
__global__ __launch_bounds__(256) void gcn64_kernel(
    const float* __restrict__ yin, const float* __restrict__ a,
    const int* __restrict__ ptr, const int2* __restrict__ ep,
    float* __restrict__ yout, const float* __restrict__ bo) {
    int bid = blockIdx.x;
    int lbid = (bid & 7) * (N_NODES / 16 / 8) + (bid >> 3);
    int t = threadIdx.x;
    int n = lbid * 16 + (t >> 4);
    int lg = t & 15;
    int c4 = lg * 4;
    int e0 = ptr[n], e1 = ptr[n + 1];
    int cnt = e1 - e0;
    float4 acc = make_float4(0.f, 0.f, 0.f, 0.f);

    int2 q[16];
#pragma unroll
    for (int i = 0; i < 16; ++i) {
        int ee = e0 + i;
        if (ee > e1 - 1) ee = e1 - 1;
        if (ee < 0) ee = 0;
        q[i] = ep[ee];
    }
#pragma unroll
    for (int i = 0; i < 16; ++i) {
        if (i < cnt) {
            float v = __int_as_float(q[i].y);
            float4 xv = *(const float4*)(yin + (size_t)q[i].x * 64 + c4);
            acc.x += v * xv.x; acc.y += v * xv.y;
            acc.z += v * xv.z; acc.w += v * xv.w;
        }
    }
    for (int e = e0 + 16; e < e1; ++e) {
        int2 qq = ep[e];
        float v = __int_as_float(qq.y);
        float4 xv = *(const float4*)(yin + (size_t)qq.x * 64 + c4);
        acc.x += v * xv.x; acc.y += v * xv.y;
        acc.z += v * xv.z; acc.w += v * xv.w;
    }

    size_t idx = (size_t)n * 64 + c4;
    float4 self = *(const float4*)(yin + idx);
    float4 at = *(const float4*)(a + idx);
    float4 o;
    o.x = self.x + 0.5f * acc.x + 0.5f * at.x;
    o.y = self.y + 0.5f * acc.y + 0.5f * at.y;
    o.z = self.z + 0.5f * acc.z + 0.5f * at.z;
    o.w = self.w + 0.5f * acc.w + 0.5f * at.w;
    if (LAST) {
        float4 bv = *(const float4*)(bo + c4);
        o.x = (o.x + bv.x) * 0.5f;
        o.y = (o.y + bv.y) * 0.5f;
        o.z = (o.z + bv.z) * 0.5f;
        o.w = (o.w + bv.w) * 0.5f;
    }
    *(float4*)(yout + idx) = o;
}

// ---------------- launch ----------------

extern "C" void kernel_launch(void* const* d_in, const int* in_sizes, int n_in,
                              void* d_out, int out_size, void* d_ws, size_t ws_size,
                              hipStream_t stream) {
    const float* x  = (const float*)d_in[0];
    const int* ei   = (const int*)d_in[1];
    const float* Wq = (const float*)d_in[3];
    const float* bq = (const float*)d_in[4];
    const float* Wk = (const float*)d_in[5];
    const float* bk = (const float*)d_in[6];
    const float* Wo = (const float*)d_in[7];
    const float* bo = (const float*)d_in[8];
    float* out = (float*)d_out;

    const int* row = ei;
    const int* col = ei + E_E;

    // bufA: [a_ (N*64)] [yA (N*64)] ; bufB: yB ; bufC: kvs partials (N*128 floats
    // = 2048*4096, consumed by kvs_reduce before anything else needs bufC).
    float* bufA = (float*)d_ws;
    float* bufB = bufA + (size_t)N_NODES * HD;
    float* bufC = bufB + (size_t)N_NODES * HD;
    int2*  ep   = (int2*)(bufC + (size_t)N_NODES * HD);
    float* kvs  = (float*)(ep + E_E);                  // 131072
    float* M    = kvs + 131072;                        // 131072
    float* Cc   = M + 131072;                          // 2048
    float* ksum = Cc + 2048;                           // 2048
    float* xsum = ksum + 2048;                         // 1024
    float* dinv = xsum + 1024;                         // N
    int* degi   = (int*)(dinv + N_NODES);              // N
    int* cursor = degi + N_NODES;                      // N
    int* ptr    = cursor + N_NODES;                    // N+1
    int* bsums  = ptr + N_NODES + 1;                   // 256

    float* a_       = bufA;
    float* yA       = bufA + (size_t)N_NODES * 64;
    float* yB       = bufB;
    float* partials = bufC;

    hipMemsetAsync(degi, 0, (size_t)N_NODES * 2 * 4, stream);
    hipMemsetAsync(ksum, 0, (size_t)(2048 + 1024) * 4, stream);

    deg_kernel<<<E_E / 256, 256, 0, stream>>>(col, degi);
    scan1<<<N_NODES / 256, 256, 0, stream>>>(degi, ptr, bsums, dinv);
    scan3<<<N_NODES / 256, 256, 0, stream>>>(ptr, bsums);
    scatter_kernel<<<E_E / 256, 256, 0, stream>>>(row, col, ptr, cursor, dinv, ep);

    kvskp_kernel<<<2048, 256, 0, stream>>>(x, Wk, bk, partials, ksum, xsum);
    kvs_reduce<<<512, 256, 0, stream>>>(partials, kvs);
    mwo_kernel<<<32, 256, 0, stream>>>(kvs, Wo, xsum, M, Cc);
    fatt_kernel<<<1024, 256, 0, stream>>>(x, Wq, bq, M, Cc, ksum, a_);

    y0_kernel<<<1024, 256, 0, stream>>>(x, Wo, yA);

    gcn64_kernel<0><<<N_NODES / 16, 256, 0, stream>>>(yA, a_, ptr, ep, yB, bo);
    gcn64_kernel<0><<<N_NODES / 16, 256, 0, stream>>>(yB, a_, ptr, ep, yA, bo);
    gcn64_kernel<0><<<N_NODES / 16, 256, 0, stream>>>(yA, a_, ptr, ep, yB, bo);
    gcn64_kernel<1><<<N_NODES / 16, 256, 0, stream>>>(yB, a_, ptr, ep, out, bo);
}